// Round 6
// baseline (17030.270 us; speedup 1.0000x reference)
//
#include <hip/hip_runtime.h>
#include <math.h>

#define VOCAB 32000
#define HID   1024
#define BATCH 8
#define SEQ   512
#define GD    (4*HID)       // 4096 gate width
#define ROWS  (BATCH*SEQ)   // 4096
#define NBLK  256           // scan grid: 256 blocks <= capacity => co-resident

typedef __attribute__((ext_vector_type(8))) short short8;
typedef __attribute__((ext_vector_type(4))) float f32x4;

// ---------------------------------------------------------------------------
// 1) Embedding gather: emb[row][h] = w_out[h][ids[row]]
// ---------------------------------------------------------------------------
__global__ __launch_bounds__(256) void k_gather(const int* __restrict__ ids,
                                                const float* __restrict__ w_out,
                                                float* __restrict__ emb)
{
    int row = blockIdx.x;            // 0..4095  (b*SEQ + s)
    int id  = ids[row];
    const float* src = w_out + id;   // column id, stride VOCAB
    float* dst = emb + (size_t)row * HID;
    for (int h = threadIdx.x; h < HID; h += 256)
        dst[h] = src[(size_t)h * VOCAB];
}

// ---------------------------------------------------------------------------
// 2) Transpose W_hh [1024][4096] -> W_hhT [4096][1024]
// ---------------------------------------------------------------------------
__global__ __launch_bounds__(256) void k_transpose(const float* __restrict__ W,
                                                   float* __restrict__ WT)
{
    __shared__ float tile[32][33];
    int bx = blockIdx.x;
    int by = blockIdx.y;
    int x = bx*32 + threadIdx.x;
    int y = by*32 + threadIdx.y;
    #pragma unroll
    for (int i = 0; i < 32; i += 8)
        tile[threadIdx.y + i][threadIdx.x] = W[(size_t)(y + i)*GD + x];
    __syncthreads();
    int k   = by*32 + threadIdx.x;
    int col = bx*32 + threadIdx.y;
    #pragma unroll
    for (int i = 0; i < 32; i += 8)
        WT[(size_t)(col + i)*HID + k] = tile[threadIdx.x][threadIdx.y + i];
}

// ---------------------------------------------------------------------------
// 3) Split-bf16 MFMA GEMM + bias:  C = A(f32)·B(f32) + bias
//    C ≈ Ahi·Bhi + Ahi·Blo + Alo·Bhi   (err ~2^-16 rel)
//    Block: 256 thr = 4 waves (2x2), 128x128 tile, BK=32.
// ---------------------------------------------------------------------------
#define GBM 128
#define GBN 128
#define GBK 32

__device__ __forceinline__ unsigned pack_hi(float x, float y) {
    return (__float_as_uint(x) >> 16) | (__float_as_uint(y) & 0xFFFF0000u);
}
__device__ __forceinline__ float hi_f32(float x) {
    return __uint_as_float(__float_as_uint(x) & 0xFFFF0000u);
}
// packed word: hi bf16 in high half, lo bf16 in low half
__device__ __forceinline__ unsigned pack_pair(float x) {
    unsigned hb = __float_as_uint(x) & 0xFFFF0000u;
    float lo = x - __uint_as_float(hb);
    return hb | (__float_as_uint(lo) >> 16);
}

__global__ __launch_bounds__(256) void k_gemm_mfma(const float* __restrict__ A,
                                                   const float* __restrict__ B,
                                                   const float* __restrict__ bias,
                                                   float* __restrict__ C,
                                                   int M, int N, int K)
{
    __shared__ unsigned short As_hi[GBM][40];
    __shared__ unsigned short As_lo[GBM][40];
    __shared__ unsigned int   Bs[GBK][130];

    int tid  = threadIdx.x;
    int brow = blockIdx.y * GBM;
    int bcol = blockIdx.x * GBN;

    int lane = tid & 63;
    int wid  = tid >> 6;
    int wm   = wid >> 1;
    int wn   = wid & 1;
    int l15  = lane & 15;
    int l4   = lane >> 4;

    int a_m = tid >> 3;
    int a_c = tid & 7;
    int b_k = tid >> 5;
    int b_n = tid & 31;

    f32x4 acc[4][4] = {};

    for (int k0 = 0; k0 < K; k0 += GBK) {
        #pragma unroll
        for (int p = 0; p < 4; ++p) {
            int r = a_m + p*32;
            float4 v = *(const float4*)(A + (size_t)(brow + r)*K + k0 + a_c*4);
            unsigned h0 = pack_hi(v.x, v.y);
            unsigned h1 = pack_hi(v.z, v.w);
            float lx = v.x - hi_f32(v.x);
            float ly = v.y - hi_f32(v.y);
            float lz = v.z - hi_f32(v.z);
            float lw = v.w - hi_f32(v.w);
            unsigned l0 = pack_hi(lx, ly);
            unsigned l1 = pack_hi(lz, lw);
            *(uint2*)&As_hi[r][a_c*4] = make_uint2(h0, h1);
            *(uint2*)&As_lo[r][a_c*4] = make_uint2(l0, l1);
        }
        #pragma unroll
        for (int p = 0; p < 4; ++p) {
            int kk = b_k + p*8;
            float4 v = *(const float4*)(B + (size_t)(k0 + kk)*N + bcol + b_n*4);
            unsigned w0 = pack_pair(v.x);
            unsigned w1 = pack_pair(v.y);
            unsigned w2 = pack_pair(v.z);
            unsigned w3 = pack_pair(v.w);
            *(uint2*)&Bs[kk][b_n*4]     = make_uint2(w0, w1);
            *(uint2*)&Bs[kk][b_n*4 + 2] = make_uint2(w2, w3);
        }
        __syncthreads();

        short8 ah[4], al[4];
        #pragma unroll
        for (int m = 0; m < 4; ++m) {
            int r = wm*64 + m*16 + l15;
            ah[m] = *(const short8*)&As_hi[r][l4*8];
            al[m] = *(const short8*)&As_lo[r][l4*8];
        }

        #pragma unroll
        for (int n = 0; n < 4; ++n) {
            int col = wn*64 + n*16 + l15;
            unsigned w[8];
            #pragma unroll
            for (int j = 0; j < 8; ++j)
                w[j] = Bs[l4*8 + j][col];
            union { short8 v; unsigned d[4]; } bh, bl;
            #pragma unroll
            for (int d = 0; d < 4; ++d) {
                bh.d[d] = (w[2*d] >> 16)      | (w[2*d+1] & 0xFFFF0000u);
                bl.d[d] = (w[2*d] & 0xFFFFu)  | (w[2*d+1] << 16);
            }
            #pragma unroll
            for (int m = 0; m < 4; ++m) {
                acc[m][n] = __builtin_amdgcn_mfma_f32_16x16x32_bf16(ah[m], bh.v, acc[m][n], 0, 0, 0);
                acc[m][n] = __builtin_amdgcn_mfma_f32_16x16x32_bf16(ah[m], bl.v, acc[m][n], 0, 0, 0);
                acc[m][n] = __builtin_amdgcn_mfma_f32_16x16x32_bf16(al[m], bh.v, acc[m][n], 0, 0, 0);
            }
        }
        __syncthreads();
    }

    #pragma unroll
    for (int n = 0; n < 4; ++n) {
        int col = bcol + wn*64 + n*16 + l15;
        float bv = bias[col];
        #pragma unroll
        for (int m = 0; m < 4; ++m) {
            int rb = brow + wm*64 + m*16 + l4*4;
            #pragma unroll
            for (int r = 0; r < 4; ++r)
                C[(size_t)(rb + r)*N + col] = acc[m][n][r] + bv;
        }
    }
}

// ---------------------------------------------------------------------------
// 4) Persistent LSTM scan — all 512 steps in ONE regular launch.
//    Co-residency by capacity: 256 blocks x 256 thr = 65K threads vs 524K
//    device capacity (VGPR ~150, LDS ~128B) -> all blocks resident, no
//    cooperative API needed.
//    Block owns 4 hidden cols; wave = gate; W_hhT slice in REGISTERS
//    (16 float4/lane). c-state in tail-thread registers. Race-free:
//    step t reads hs[t-1], writes hs[t] (disjoint).
//    Grid sync: per-step counter bar[t] (zeroed by hipMemsetAsync each
//    call), GFX9 release/acquire: syncthreads -> threadfence(wb L2) ->
//    atomicAdd -> spin -> syncthreads -> threadfence(inv L1).
// ---------------------------------------------------------------------------
__global__ __launch_bounds__(256) void k_lstm_scan(
    const float* __restrict__ xg, const float* __restrict__ WT,
    float* __restrict__ hs, unsigned int* __restrict__ bar)
{
    const int tid  = threadIdx.x;
    const int gate = tid >> 6;        // 0..3 (wave = gate)
    const int lane = tid & 63;
    const int j0   = blockIdx.x * 4;  // 4 hidden cols per block

    // W in registers: 4 cols x 4 float4; k4 = c*64 + lane (coalesced load)
    float4 w[4][4];
    #pragma unroll
    for (int jl = 0; jl < 4; ++jl) {
        const float4* wp = (const float4*)(WT + (size_t)(gate*HID + j0 + jl)*HID);
        #pragma unroll
        for (int c = 0; c < 4; ++c)
            w[jl][c] = wp[c*64 + lane];
    }

    float creg = 0.0f;                // c-state for tail threads (tid<32)
    __shared__ float g_sm[4][4][8];   // [gate][col][batch]

    for (int t = 0; t < SEQ; ++t) {
        float acc[4][8] = {};
        if (t > 0) {
            #pragma unroll
            for (int c = 0; c < 4; ++c) {
                int k4 = c*64 + lane;
                #pragma unroll
                for (int b = 0; b < 8; ++b) {
                    float4 h4 = ((const float4*)(hs + ((size_t)b*SEQ + (t-1))*HID))[k4];
                    #pragma unroll
                    for (int jl = 0; jl < 4; ++jl)
                        acc[jl][b] += w[jl][c].x*h4.x + w[jl][c].y*h4.y
                                    + w[jl][c].z*h4.z + w[jl][c].w*h4.w;
                }
            }
            #pragma unroll
            for (int jl = 0; jl < 4; ++jl)
                #pragma unroll
                for (int b = 0; b < 8; ++b) {
                    float v = acc[jl][b];
                    v += __shfl_xor(v, 32);
                    v += __shfl_xor(v, 16);
                    v += __shfl_xor(v, 8);
                    v += __shfl_xor(v, 4);
                    v += __shfl_xor(v, 2);
                    v += __shfl_xor(v, 1);
                    acc[jl][b] = v;
                }
        }
        if (lane == 0) {
            #pragma unroll
            for (int jl = 0; jl < 4; ++jl)
                #pragma unroll
                for (int b = 0; b < 8; ++b)
                    g_sm[gate][jl][b] = acc[jl][b];
        }
        __syncthreads();

        if (tid < 32) {
            int b  = tid & 7;
            int jl = tid >> 3;        // 0..3
            int j  = j0 + jl;
            size_t xbase = ((size_t)b*SEQ + t)*GD + j;
            float iv = g_sm[0][jl][b] + xg[xbase];
            float fv = g_sm[1][jl][b] + xg[xbase + HID];
            float gv = g_sm[2][jl][b] + xg[xbase + 2*HID];
            float ov = g_sm[3][jl][b] + xg[xbase + 3*HID];
            iv = 1.0f / (1.0f + expf(-iv));
            fv = 1.0f / (1.0f + expf(-fv));
            gv = tanhf(gv);
            ov = 1.0f / (1.0f + expf(-ov));
            float cn = fv*creg + iv*gv;
            creg = cn;
            hs[((size_t)b*SEQ + t)*HID + j] = ov * tanhf(cn);
        }

        if (t < SEQ-1) {
            __syncthreads();              // all tail stores issued & drained
            if (tid == 0) {
                __threadfence();          // release: L2 writeback to coherent pt
                atomicAdd(&bar[t], 1u);   // device-scope by default
                while (__hip_atomic_load(&bar[t], __ATOMIC_RELAXED,
                                         __HIP_MEMORY_SCOPE_AGENT) < NBLK)
                    __builtin_amdgcn_s_sleep(2);
            }
            __syncthreads();              // everyone waits for tid0's spin
            __threadfence();              // acquire: invalidate L1
        }
    }
}

// ---------------------------------------------------------------------------
// Launch
// ---------------------------------------------------------------------------
extern "C" void kernel_launch(void* const* d_in, const int* in_sizes, int n_in,
                              void* d_out, int out_size, void* d_ws, size_t ws_size,
                              hipStream_t stream)
{
    const int*   ids    = (const int*)  d_in[0];
    const float* w_out  = (const float*)d_in[1];
    const float* b_out  = (const float*)d_in[2];
    const float* W_ih   = (const float*)d_in[3];
    const float* W_hh   = (const float*)d_in[4];
    const float* b_lstm = (const float*)d_in[5];
    float* out = (float*)d_out;

    // Scratch carved from d_out (524 MB; every region dead before the final
    // GEMM overwrites d_out). hs (read during the final GEMM) lives in d_ws.
    char* ob = (char*)d_out;
    float* emb    = (float*)(ob);                 // 16,777,216 B
    float* WT     = (float*)(ob + 16777216);      // 16,777,216 B
    float* xg     = (float*)(ob + 33554432);      // 67,108,864 B
    unsigned int* bar = (unsigned int*)(ob + 100663296); // SEQ*4 = 2048 B
    float* hs     = (float*)d_ws;                 // 16,777,216 B

    // 1) embedding gather
    k_gather<<<ROWS, 256, 0, stream>>>(ids, w_out, emb);

    // 2) transpose W_hh for contiguous per-column dots in the scan
    k_transpose<<<dim3(GD/32, HID/32), dim3(32, 8), 0, stream>>>(W_hh, WT);

    // 3) x_gates = emb @ W_ih + b_lstm   [4096 x 4096]  (split-bf16 MFMA)
    k_gemm_mfma<<<dim3(GD/GBN, ROWS/GBM), 256, 0, stream>>>(
        emb, W_ih, b_lstm, xg, ROWS, GD, HID);

    // 4) persistent scan, one regular launch (barrier counters zeroed first)
    hipMemsetAsync((void*)bar, 0, SEQ * sizeof(unsigned int), stream);
    k_lstm_scan<<<NBLK, 256, 0, stream>>>(xg, WT, hs, bar);

    // 5) logits = hs @ w_out + b_out   [4096 x 32000]  (split-bf16 MFMA)
    k_gemm_mfma<<<dim3(VOCAB/GBN, ROWS/GBM), 256, 0, stream>>>(
        hs, w_out, b_out, out, ROWS, VOCAB, HID);
}

// Round 7
// 5312.785 us; speedup vs baseline: 3.2055x; 3.2055x over previous
//
#include <hip/hip_runtime.h>
#include <math.h>

#define VOCAB 32000
#define HID   1024
#define BATCH 8
#define SEQ   512
#define GD    (4*HID)       // 4096 gate width
#define ROWS  (BATCH*SEQ)   // 4096

typedef __attribute__((ext_vector_type(8))) short short8;
typedef __attribute__((ext_vector_type(4))) float f32x4;

__device__ __forceinline__ float hi_f32(float x) {
    return __uint_as_float(__float_as_uint(x) & 0xFFFF0000u);
}
// packed word: hi bf16 bits in high half, lo bf16 bits in low half
__device__ __forceinline__ unsigned pack_pair(float x) {
    unsigned hb = __float_as_uint(x) & 0xFFFF0000u;
    float lo = x - __uint_as_float(hb);
    return hb | (__float_as_uint(lo) >> 16);
}

// ---------------------------------------------------------------------------
// 1) Embedding gather, split form: emb_hi/lo[row][h] = split(w_out[h][ids[row]])
// ---------------------------------------------------------------------------
__global__ __launch_bounds__(256) void k_gather_split(const int* __restrict__ ids,
                                                      const float* __restrict__ w_out,
                                                      unsigned short* __restrict__ emb_hi,
                                                      unsigned short* __restrict__ emb_lo)
{
    int row = blockIdx.x;            // 0..4095
    int id  = ids[row];
    const float* src = w_out + id;   // column id, stride VOCAB
    for (int h = threadIdx.x; h < HID; h += 256) {
        float v  = src[(size_t)h * VOCAB];
        float hi = hi_f32(v);
        float lo = v - hi;
        emb_hi[(size_t)row*HID + h] = (unsigned short)(__float_as_uint(v)  >> 16);
        emb_lo[(size_t)row*HID + h] = (unsigned short)(__float_as_uint(lo) >> 16);
    }
}

// ---------------------------------------------------------------------------
// 2) Transpose W_hh [1024][4096] -> W_hhT [4096][1024]  (fp32, for the scan)
// ---------------------------------------------------------------------------
__global__ __launch_bounds__(256) void k_transpose(const float* __restrict__ W,
                                                   float* __restrict__ WT)
{
    __shared__ float tile[32][33];
    int bx = blockIdx.x;
    int by = blockIdx.y;
    int x = bx*32 + threadIdx.x;
    int y = by*32 + threadIdx.y;
    #pragma unroll
    for (int i = 0; i < 32; i += 8)
        tile[threadIdx.y + i][threadIdx.x] = W[(size_t)(y + i)*GD + x];
    __syncthreads();
    int k   = by*32 + threadIdx.x;
    int col = bx*32 + threadIdx.y;
    #pragma unroll
    for (int i = 0; i < 32; i += 8)
        WT[(size_t)(col + i)*HID + k] = tile[threadIdx.x][threadIdx.y + i];
}

// ---------------------------------------------------------------------------
// 2b) Pack fp32 -> (hi|lo) u32, elementwise (grid-stride, float4)
// ---------------------------------------------------------------------------
__global__ __launch_bounds__(256) void k_pack_pairs(const float* __restrict__ src,
                                                    unsigned int* __restrict__ dst,
                                                    long n4)   // count of float4
{
    long i0 = (long)blockIdx.x * 256 + threadIdx.x;
    long stride = (long)gridDim.x * 256;
    for (long i = i0; i < n4; i += stride) {
        float4 v = ((const float4*)src)[i];
        uint4 o;
        o.x = pack_pair(v.x); o.y = pack_pair(v.y);
        o.z = pack_pair(v.z); o.w = pack_pair(v.w);
        ((uint4*)dst)[i] = o;
    }
}

// ---------------------------------------------------------------------------
// 2c) Split fp32 -> hi bf16, lo bf16 arrays (grid-stride, float4)
// ---------------------------------------------------------------------------
__global__ __launch_bounds__(256) void k_split_f32(const float* __restrict__ src,
                                                   unsigned short* __restrict__ hi,
                                                   unsigned short* __restrict__ lo,
                                                   long n4)
{
    long i0 = (long)blockIdx.x * 256 + threadIdx.x;
    long stride = (long)gridDim.x * 256;
    for (long i = i0; i < n4; i += stride) {
        float4 v = ((const float4*)src)[i];
        unsigned h0 = __float_as_uint(v.x) >> 16, h1 = __float_as_uint(v.y) >> 16;
        unsigned h2 = __float_as_uint(v.z) >> 16, h3 = __float_as_uint(v.w) >> 16;
        unsigned l0 = __float_as_uint(v.x - hi_f32(v.x)) >> 16;
        unsigned l1 = __float_as_uint(v.y - hi_f32(v.y)) >> 16;
        unsigned l2 = __float_as_uint(v.z - hi_f32(v.z)) >> 16;
        unsigned l3 = __float_as_uint(v.w - hi_f32(v.w)) >> 16;
        ((uint2*)hi)[i] = make_uint2(h0 | (h1 << 16), h2 | (h3 << 16));
        ((uint2*)lo)[i] = make_uint2(l0 | (l1 << 16), l2 | (l3 << 16));
    }
}

// ---------------------------------------------------------------------------
// 3) Split-bf16 MFMA GEMM + bias, PRE-CONVERTED operands (bit-identical math
//    to the in-kernel-converting version):
//    C ≈ Ahi·Bhi + Ahi·Blo + Alo·Bhi + bias
//    Ah/Al: [M][K] bf16 bits; Bpk: [K][N] packed (hi|lo) u32.
// ---------------------------------------------------------------------------
#define GBM 128
#define GBN 128
#define GBK 32

__global__ __launch_bounds__(256) void k_gemm_pre(const unsigned short* __restrict__ Ah,
                                                  const unsigned short* __restrict__ Al,
                                                  const unsigned int* __restrict__ Bpk,
                                                  const float* __restrict__ bias,
                                                  float* __restrict__ C,
                                                  int M, int N, int K)
{
    __shared__ unsigned short As_hi[GBM][40];   // 80B pitch (16B aligned)
    __shared__ unsigned short As_lo[GBM][40];
    __shared__ unsigned int   Bs[GBK][132];     // 528B pitch (16B aligned)

    int tid  = threadIdx.x;
    int brow = blockIdx.y * GBM;
    int bcol = blockIdx.x * GBN;

    int lane = tid & 63;
    int wid  = tid >> 6;
    int wm   = wid >> 1;
    int wn   = wid & 1;
    int l15  = lane & 15;
    int l4   = lane >> 4;

    int a_m = tid >> 3;           // 0..31
    int a_c = tid & 7;            // 4-elem chunk in k
    int b_k = tid >> 5;           // 0..7
    int b_n = tid & 31;           // 4-word chunk in n

    f32x4 acc[4][4] = {};

    for (int k0 = 0; k0 < K; k0 += GBK) {
        #pragma unroll
        for (int p = 0; p < 4; ++p) {
            int r = a_m + p*32;
            *(uint2*)&As_hi[r][a_c*4] =
                *(const uint2*)(Ah + (size_t)(brow + r)*K + k0 + a_c*4);
            *(uint2*)&As_lo[r][a_c*4] =
                *(const uint2*)(Al + (size_t)(brow + r)*K + k0 + a_c*4);
        }
        #pragma unroll
        for (int p = 0; p < 4; ++p) {
            int kk = b_k + p*8;
            *(uint4*)&Bs[kk][b_n*4] =
                *(const uint4*)(Bpk + (size_t)(k0 + kk)*N + bcol + b_n*4);
        }
        __syncthreads();

        short8 ah[4], al[4];
        #pragma unroll
        for (int m = 0; m < 4; ++m) {
            int r = wm*64 + m*16 + l15;
            ah[m] = *(const short8*)&As_hi[r][l4*8];
            al[m] = *(const short8*)&As_lo[r][l4*8];
        }

        #pragma unroll
        for (int n = 0; n < 4; ++n) {
            int col = wn*64 + n*16 + l15;
            unsigned w[8];
            #pragma unroll
            for (int j = 0; j < 8; ++j)
                w[j] = Bs[l4*8 + j][col];
            union { short8 v; unsigned d[4]; } bh, bl;
            #pragma unroll
            for (int d = 0; d < 4; ++d) {
                bh.d[d] = (w[2*d] >> 16)      | (w[2*d+1] & 0xFFFF0000u);
                bl.d[d] = (w[2*d] & 0xFFFFu)  | (w[2*d+1] << 16);
            }
            #pragma unroll
            for (int m = 0; m < 4; ++m) {
                acc[m][n] = __builtin_amdgcn_mfma_f32_16x16x32_bf16(ah[m], bh.v, acc[m][n], 0, 0, 0);
                acc[m][n] = __builtin_amdgcn_mfma_f32_16x16x32_bf16(ah[m], bl.v, acc[m][n], 0, 0, 0);
                acc[m][n] = __builtin_amdgcn_mfma_f32_16x16x32_bf16(al[m], bh.v, acc[m][n], 0, 0, 0);
            }
        }
        __syncthreads();
    }

    #pragma unroll
    for (int n = 0; n < 4; ++n) {
        int col = bcol + wn*64 + n*16 + l15;
        float bv = bias[col];
        #pragma unroll
        for (int m = 0; m < 4; ++m) {
            int rb = brow + wm*64 + m*16 + l4*4;
            #pragma unroll
            for (int r = 0; r < 4; ++r)
                C[(size_t)(rb + r)*N + col] = acc[m][n][r] + bv;
        }
    }
}

// ---------------------------------------------------------------------------
// 3b) Fallback GEMM (in-kernel conversion) — exact Round-4 kernel, used for
//     the final GEMM when ws_size is too small for packed w_out.
// ---------------------------------------------------------------------------
__device__ __forceinline__ unsigned pack_hi2(float x, float y) {
    return (__float_as_uint(x) >> 16) | (__float_as_uint(y) & 0xFFFF0000u);
}

__global__ __launch_bounds__(256) void k_gemm_mfma(const float* __restrict__ A,
                                                   const float* __restrict__ B,
                                                   const float* __restrict__ bias,
                                                   float* __restrict__ C,
                                                   int M, int N, int K)
{
    __shared__ unsigned short As_hi[GBM][40];
    __shared__ unsigned short As_lo[GBM][40];
    __shared__ unsigned int   Bs[GBK][130];

    int tid  = threadIdx.x;
    int brow = blockIdx.y * GBM;
    int bcol = blockIdx.x * GBN;

    int lane = tid & 63;
    int wid  = tid >> 6;
    int wm   = wid >> 1;
    int wn   = wid & 1;
    int l15  = lane & 15;
    int l4   = lane >> 4;

    int a_m = tid >> 3;
    int a_c = tid & 7;
    int b_k = tid >> 5;
    int b_n = tid & 31;

    f32x4 acc[4][4] = {};

    for (int k0 = 0; k0 < K; k0 += GBK) {
        #pragma unroll
        for (int p = 0; p < 4; ++p) {
            int r = a_m + p*32;
            float4 v = *(const float4*)(A + (size_t)(brow + r)*K + k0 + a_c*4);
            unsigned h0 = pack_hi2(v.x, v.y);
            unsigned h1 = pack_hi2(v.z, v.w);
            float lx = v.x - hi_f32(v.x);
            float ly = v.y - hi_f32(v.y);
            float lz = v.z - hi_f32(v.z);
            float lw = v.w - hi_f32(v.w);
            unsigned l0 = pack_hi2(lx, ly);
            unsigned l1 = pack_hi2(lz, lw);
            *(uint2*)&As_hi[r][a_c*4] = make_uint2(h0, h1);
            *(uint2*)&As_lo[r][a_c*4] = make_uint2(l0, l1);
        }
        #pragma unroll
        for (int p = 0; p < 4; ++p) {
            int kk = b_k + p*8;
            float4 v = *(const float4*)(B + (size_t)(k0 + kk)*N + bcol + b_n*4);
            unsigned w0 = pack_pair(v.x);
            unsigned w1 = pack_pair(v.y);
            unsigned w2 = pack_pair(v.z);
            unsigned w3 = pack_pair(v.w);
            *(uint2*)&Bs[kk][b_n*4]     = make_uint2(w0, w1);
            *(uint2*)&Bs[kk][b_n*4 + 2] = make_uint2(w2, w3);
        }
        __syncthreads();

        short8 ah[4], al[4];
        #pragma unroll
        for (int m = 0; m < 4; ++m) {
            int r = wm*64 + m*16 + l15;
            ah[m] = *(const short8*)&As_hi[r][l4*8];
            al[m] = *(const short8*)&As_lo[r][l4*8];
        }

        #pragma unroll
        for (int n = 0; n < 4; ++n) {
            int col = wn*64 + n*16 + l15;
            unsigned w[8];
            #pragma unroll
            for (int j = 0; j < 8; ++j)
                w[j] = Bs[l4*8 + j][col];
            union { short8 v; unsigned d[4]; } bh, bl;
            #pragma unroll
            for (int d = 0; d < 4; ++d) {
                bh.d[d] = (w[2*d] >> 16)      | (w[2*d+1] & 0xFFFF0000u);
                bl.d[d] = (w[2*d] & 0xFFFFu)  | (w[2*d+1] << 16);
            }
            #pragma unroll
            for (int m = 0; m < 4; ++m) {
                acc[m][n] = __builtin_amdgcn_mfma_f32_16x16x32_bf16(ah[m], bh.v, acc[m][n], 0, 0, 0);
                acc[m][n] = __builtin_amdgcn_mfma_f32_16x16x32_bf16(ah[m], bl.v, acc[m][n], 0, 0, 0);
                acc[m][n] = __builtin_amdgcn_mfma_f32_16x16x32_bf16(al[m], bh.v, acc[m][n], 0, 0, 0);
            }
        }
        __syncthreads();
    }

    #pragma unroll
    for (int n = 0; n < 4; ++n) {
        int col = bcol + wn*64 + n*16 + l15;
        float bv = bias[col];
        #pragma unroll
        for (int m = 0; m < 4; ++m) {
            int rb = brow + wm*64 + m*16 + l4*4;
            #pragma unroll
            for (int r = 0; r < 4; ++r)
                C[(size_t)(rb + r)*N + col] = acc[m][n][r] + bv;
        }
    }
}

// ---------------------------------------------------------------------------
// 4) One LSTM timestep — Round-4 version verbatim (proven, 5.5 us/step).
//    1024 blocks x 256 thr; block = hidden col j; wave = gate; coalesced W
//    column read; per-batch register accumulators; butterfly reduce.
//    Race-free: reads hs[t-1], writes hs[t].
// ---------------------------------------------------------------------------
__global__ __launch_bounds__(256) void k_lstm_step(const float* __restrict__ xg,
                                                   const float* __restrict__ WT,
                                                   float* __restrict__ c_state,
                                                   float* __restrict__ hs,
                                                   int t)
{
    int j    = blockIdx.x;            // hidden col 0..1023
    int gate = threadIdx.x >> 6;      // 0..3 (i,f,g,o)
    int lane = threadIdx.x & 63;
    int col  = gate*HID + j;

    float acc[8] = {};
    if (t > 0) {
        const float4* wv = (const float4*)(WT + (size_t)col*HID);
        #pragma unroll
        for (int c = 0; c < 4; ++c) {
            int k4 = c*64 + lane;
            float4 w4 = wv[k4];
            #pragma unroll
            for (int b = 0; b < 8; ++b) {
                float4 h4 = ((const float4*)(hs + ((size_t)b*SEQ + (t-1))*HID))[k4];
                acc[b] += w4.x*h4.x + w4.y*h4.y + w4.z*h4.z + w4.w*h4.w;
            }
        }
        #pragma unroll
        for (int b = 0; b < 8; ++b) {
            acc[b] += __shfl_xor(acc[b], 32);
            acc[b] += __shfl_xor(acc[b], 16);
            acc[b] += __shfl_xor(acc[b], 8);
            acc[b] += __shfl_xor(acc[b], 4);
            acc[b] += __shfl_xor(acc[b], 2);
            acc[b] += __shfl_xor(acc[b], 1);
        }
    }

    __shared__ float g_sm[4][8];
    if (lane == 0) {
        #pragma unroll
        for (int b = 0; b < 8; ++b)
            g_sm[gate][b] = acc[b];
    }
    __syncthreads();

    if (threadIdx.x < 8) {
        int b = threadIdx.x;
        size_t xbase = ((size_t)b*SEQ + t)*GD + j;
        float iv = g_sm[0][b] + xg[xbase];
        float fv = g_sm[1][b] + xg[xbase + HID];
        float gv = g_sm[2][b] + xg[xbase + 2*HID];
        float ov = g_sm[3][b] + xg[xbase + 3*HID];
        iv = 1.0f / (1.0f + expf(-iv));
        fv = 1.0f / (1.0f + expf(-fv));
        gv = tanhf(gv);
        ov = 1.0f / (1.0f + expf(-ov));
        float c  = (t > 0) ? c_state[(size_t)b*HID + j] : 0.0f;
        float cn = fv*c + iv*gv;
        float hn = ov * tanhf(cn);
        c_state[(size_t)b*HID + j] = cn;
        hs[((size_t)b*SEQ + t)*HID + j] = hn;
    }
}

// ---------------------------------------------------------------------------
// Launch
// ---------------------------------------------------------------------------
extern "C" void kernel_launch(void* const* d_in, const int* in_sizes, int n_in,
                              void* d_out, int out_size, void* d_ws, size_t ws_size,
                              hipStream_t stream)
{
    const int*   ids    = (const int*)  d_in[0];
    const float* w_out  = (const float*)d_in[1];
    const float* b_out  = (const float*)d_in[2];
    const float* W_ih   = (const float*)d_in[3];
    const float* W_hh   = (const float*)d_in[4];
    const float* b_lstm = (const float*)d_in[5];
    float* out = (float*)d_out;

    // d_out scratch: all regions DEAD before the final GEMM writes C.
    char* ob = (char*)d_out;
    unsigned short* emb_hi = (unsigned short*)(ob);              //  8,388,608 B
    unsigned short* emb_lo = (unsigned short*)(ob + 8388608);    //  8,388,608 B
    float*          WT     = (float*)(ob + 16777216);            // 16,777,216 B
    float*          xg     = (float*)(ob + 33554432);            // 67,108,864 B
    float*          cstate = (float*)(ob + 100663296);           //     32,768 B
    unsigned int*   wih_pk = (unsigned int*)(ob + 100696064);    // 16,777,216 B

    // d_ws: hs (alive through final GEMM). Packed w_out + split hs only if
    // the workspace is big enough; else fall back to in-kernel conversion.
    char* wb = (char*)d_ws;
    float* hs = (float*)wb;                                      // 16,777,216 B
    const size_t NEED = 16777216ull + 8388608ull*2 + (size_t)VOCAB*HID*4ull;
    const bool big_ws = (ws_size >= NEED);
    unsigned short* hs_hi = (unsigned short*)(wb + 16777216);
    unsigned short* hs_lo = (unsigned short*)(wb + 25165824);
    unsigned int*   wo_pk = (unsigned int*)(wb + 33554432);      // 131,072,000 B

    // 1) embedding gather (split to hi/lo bf16 directly)
    k_gather_split<<<ROWS, 256, 0, stream>>>(ids, w_out, emb_hi, emb_lo);

    // 2) transpose W_hh (fp32) for the scan
    k_transpose<<<dim3(GD/32, HID/32), dim3(32, 8), 0, stream>>>(W_hh, WT);

    // 2b) pack W_ih -> (hi|lo) u32
    k_pack_pairs<<<1024, 256, 0, stream>>>(W_ih, wih_pk, (long)HID*GD/4);

    // 3) x_gates = emb @ W_ih + b_lstm  (pre-converted split-bf16 MFMA)
    k_gemm_pre<<<dim3(GD/GBN, ROWS/GBM), 256, 0, stream>>>(
        emb_hi, emb_lo, wih_pk, b_lstm, xg, ROWS, GD, HID);

    // 4) sequential LSTM scan: 512 launches (launch boundary = cheap barrier)
    for (int t = 0; t < SEQ; ++t)
        k_lstm_step<<<HID, 256, 0, stream>>>(xg, WT, cstate, hs, t);

    // 5) logits = hs @ w_out + b_out
    if (big_ws) {
        k_pack_pairs<<<2048, 256, 0, stream>>>(w_out, wo_pk, (long)HID*VOCAB/4);
        k_split_f32<<<1024, 256, 0, stream>>>(hs, hs_hi, hs_lo, (long)ROWS*HID/4);
        k_gemm_pre<<<dim3(VOCAB/GBN, ROWS/GBM), 256, 0, stream>>>(
            hs_hi, hs_lo, wo_pk, b_out, out, ROWS, VOCAB, HID);
    } else {
        k_gemm_mfma<<<dim3(VOCAB/GBN, ROWS/GBM), 256, 0, stream>>>(
            hs, w_out, b_out, out, ROWS, VOCAB, HID);
    }
}

// Round 8
// 5221.019 us; speedup vs baseline: 3.2619x; 1.0176x over previous
//
#include <hip/hip_runtime.h>
#include <math.h>

#define VOCAB 32000
#define HID   1024
#define BATCH 8
#define SEQ   512
#define GD    (4*HID)       // 4096 gate width
#define ROWS  (BATCH*SEQ)   // 4096

typedef __attribute__((ext_vector_type(8))) short short8;
typedef __attribute__((ext_vector_type(4))) float f32x4;

__device__ __forceinline__ float hi_f32(float x) {
    return __uint_as_float(__float_as_uint(x) & 0xFFFF0000u);
}
// packed word: hi bf16 bits in high half, lo bf16 bits in low half
__device__ __forceinline__ unsigned pack_pair(float x) {
    unsigned hb = __float_as_uint(x) & 0xFFFF0000u;
    float lo = x - __uint_as_float(hb);
    return hb | (__float_as_uint(lo) >> 16);
}
__device__ __forceinline__ unsigned pack_hi2(float x, float y) {
    return (__float_as_uint(x) >> 16) | (__float_as_uint(y) & 0xFFFF0000u);
}

// async 16B/lane global->LDS (dest = wave-uniform base + lane*16)
__device__ __forceinline__ void gload16(const void* g, void* l) {
    __builtin_amdgcn_global_load_lds(
        (__attribute__((address_space(1))) void*)g,
        (__attribute__((address_space(3))) void*)l, 16, 0, 0);
}

// ---------------------------------------------------------------------------
// 1) Embedding gather, split: emb_hi/lo[row][h] = split(w_out[h][ids[row]])
// ---------------------------------------------------------------------------
__global__ __launch_bounds__(256) void k_gather_split(const int* __restrict__ ids,
                                                      const float* __restrict__ w_out,
                                                      unsigned short* __restrict__ emb_hi,
                                                      unsigned short* __restrict__ emb_lo)
{
    int row = blockIdx.x;            // 0..4095
    int id  = ids[row];
    const float* src = w_out + id;   // column id, stride VOCAB
    for (int h = threadIdx.x; h < HID; h += 256) {
        float v  = src[(size_t)h * VOCAB];
        float lo = v - hi_f32(v);
        emb_hi[(size_t)row*HID + h] = (unsigned short)(__float_as_uint(v)  >> 16);
        emb_lo[(size_t)row*HID + h] = (unsigned short)(__float_as_uint(lo) >> 16);
    }
}

// ---------------------------------------------------------------------------
// 2) Transpose W_hh [1024][4096] -> W_hhT [4096][1024] (fp32, for the scan)
// ---------------------------------------------------------------------------
__global__ __launch_bounds__(256) void k_transpose(const float* __restrict__ W,
                                                   float* __restrict__ WT)
{
    __shared__ float tile[32][33];
    int tx = threadIdx.x, ty = threadIdx.y;
    int x = blockIdx.x*32 + tx;
    int y = blockIdx.y*32 + ty;
    #pragma unroll
    for (int i = 0; i < 32; i += 8)
        tile[ty + i][tx] = W[(size_t)(y + i)*GD + x];
    __syncthreads();
    int k   = blockIdx.y*32 + tx;
    int col = blockIdx.x*32 + ty;
    #pragma unroll
    for (int i = 0; i < 32; i += 8)
        WT[(size_t)(col + i)*HID + k] = tile[tx][ty + i];
}

// ---------------------------------------------------------------------------
// 2b) Transpose + split: W[K=1024][N] f32 -> hiT/loT[N][1024] bf16 bits
// ---------------------------------------------------------------------------
__global__ __launch_bounds__(256) void k_transsplit(const float* __restrict__ W,
                                                    unsigned short* __restrict__ hiT,
                                                    unsigned short* __restrict__ loT,
                                                    int N)
{
    __shared__ float tile[32][33];
    int tx = threadIdx.x, ty = threadIdx.y;
    int x = blockIdx.x*32 + tx;      // N
    int y = blockIdx.y*32 + ty;      // K
    #pragma unroll
    for (int i = 0; i < 32; i += 8)
        tile[ty + i][tx] = W[(size_t)(y + i)*N + x];
    __syncthreads();
    int n = blockIdx.x*32 + ty;
    int k = blockIdx.y*32 + tx;
    #pragma unroll
    for (int i = 0; i < 32; i += 8) {
        float v  = tile[tx][ty + i];
        float lo = v - hi_f32(v);
        hiT[(size_t)(n + i)*HID + k] = (unsigned short)(__float_as_uint(v)  >> 16);
        loT[(size_t)(n + i)*HID + k] = (unsigned short)(__float_as_uint(lo) >> 16);
    }
}

// ---------------------------------------------------------------------------
// 2c) Split fp32 -> hi bf16, lo bf16 arrays (grid-stride, float4)
// ---------------------------------------------------------------------------
__global__ __launch_bounds__(256) void k_split_f32(const float* __restrict__ src,
                                                   unsigned short* __restrict__ hi,
                                                   unsigned short* __restrict__ lo,
                                                   long n4)
{
    long i0 = (long)blockIdx.x * 256 + threadIdx.x;
    long stride = (long)gridDim.x * 256;
    for (long i = i0; i < n4; i += stride) {
        float4 v = ((const float4*)src)[i];
        unsigned h0 = __float_as_uint(v.x) >> 16, h1 = __float_as_uint(v.y) >> 16;
        unsigned h2 = __float_as_uint(v.z) >> 16, h3 = __float_as_uint(v.w) >> 16;
        unsigned l0 = __float_as_uint(v.x - hi_f32(v.x)) >> 16;
        unsigned l1 = __float_as_uint(v.y - hi_f32(v.y)) >> 16;
        unsigned l2 = __float_as_uint(v.z - hi_f32(v.z)) >> 16;
        unsigned l3 = __float_as_uint(v.w - hi_f32(v.w)) >> 16;
        ((uint2*)hi)[i] = make_uint2(h0 | (h1 << 16), h2 | (h3 << 16));
        ((uint2*)lo)[i] = make_uint2(l0 | (l1 << 16), l2 | (l3 << 16));
    }
}

// ---------------------------------------------------------------------------
// 3) Fast split-bf16 MFMA GEMM, all operands K-major bf16 bits:
//    C = (Ah+Al)·(Bh+Bl)^T-ish: acc = Ah·Bh + Ah·Bl + Al·Bh  (+bias)
//    A:[M][K], BT:[N][K]. 128x128 tile, BK=32, 4 waves (2x2), 64x64/wave.
//    Staging: global_load_lds 16B/lane into XOR-swizzled linear LDS
//    (chunk16 c8 stored at c8^(g&7) within each 128B group g; the global
//    SOURCE is pre-swizzled so the linear DMA lands data where the swizzled
//    ds_read expects it — both-sides-or-neither).
// ---------------------------------------------------------------------------
#define GBM 128
#define GBN 128
#define GBK 32

__global__ __launch_bounds__(256) void k_gemm_fast(
    const unsigned short* __restrict__ Ah,  const unsigned short* __restrict__ Al,
    const unsigned short* __restrict__ BhT, const unsigned short* __restrict__ BlT,
    const float* __restrict__ bias, float* __restrict__ C,
    int M, int N, int K)
{
    __shared__ __align__(16) unsigned short lds[4][4096];  // Ah,Al,Bh,Bl: 8KB each

    const int tid  = threadIdx.x;
    const int lane = tid & 63;
    const int wid  = tid >> 6;
    const int wm = wid >> 1, wn = wid & 1;
    const int l15 = lane & 15, l4 = lane >> 4;
    const int brow = blockIdx.y * GBM;
    const int bcol = blockIdx.x * GBN;

    // --- staging geometry: wave fills chunks {2*wid, 2*wid+1} of each tile ---
    // LDS slot (g = 128B group, q = 16B sub-chunk) holds element chunk
    // c8 = q ^ (g&7);  r = 2g + (c8>>2);  k-chunk = c8&3 (8 bf16).
    const int lhi  = lane >> 3;              // 0..7
    const int c8   = (lane & 7) ^ lhi;       // (g&7) == lhi for both chunks
    const int koff = (c8 & 3) * 8;           // element offset in k
    const int r0   = 32*wid + 2*lhi + (c8 >> 2);
    const int r1   = r0 + 16;
    const size_t a0 = (size_t)(brow + r0)*K + koff;
    const size_t a1 = (size_t)(brow + r1)*K + koff;
    const size_t b0 = (size_t)(bcol + r0)*K + koff;
    const size_t b1 = (size_t)(bcol + r1)*K + koff;
    char* lbase = (char*)&lds[0][0];
    const int cb0 = wid*2048, cb1 = wid*2048 + 1024;  // wave-uniform chunk bases

    // --- frag read addressing (row-invariant parts fold to +1024 per frag) ---
    const int ra = wm*64 + l15;
    const int ga = ra >> 1;
    const int abyte = ga*128 + (((((ra & 1) << 2) | l4) ^ (ga & 7)) << 4);
    const int rb = wn*64 + l15;
    const int gb = rb >> 1;
    const int bbyte = gb*128 + (((((rb & 1) << 2) | l4) ^ (gb & 7)) << 4);

    f32x4 acc[4][4] = {};

    for (int k0 = 0; k0 < K; k0 += GBK) {
        gload16(Ah  + a0 + k0, lbase         + cb0);
        gload16(Ah  + a1 + k0, lbase         + cb1);
        gload16(Al  + a0 + k0, lbase + 8192  + cb0);
        gload16(Al  + a1 + k0, lbase + 8192  + cb1);
        gload16(BhT + b0 + k0, lbase + 16384 + cb0);
        gload16(BhT + b1 + k0, lbase + 16384 + cb1);
        gload16(BlT + b0 + k0, lbase + 24576 + cb0);
        gload16(BlT + b1 + k0, lbase + 24576 + cb1);
        __syncthreads();   // compiler emits vmcnt(0) drain before s_barrier

        short8 ah[4], al[4], bh[4], bl[4];
        #pragma unroll
        for (int m = 0; m < 4; ++m) {
            ah[m] = *(const short8*)(lbase         + abyte + m*1024);
            al[m] = *(const short8*)(lbase + 8192  + abyte + m*1024);
        }
        #pragma unroll
        for (int n = 0; n < 4; ++n) {
            bh[n] = *(const short8*)(lbase + 16384 + bbyte + n*1024);
            bl[n] = *(const short8*)(lbase + 24576 + bbyte + n*1024);
        }
        #pragma unroll
        for (int n = 0; n < 4; ++n)
            #pragma unroll
            for (int m = 0; m < 4; ++m) {
                acc[m][n] = __builtin_amdgcn_mfma_f32_16x16x32_bf16(ah[m], bh[n], acc[m][n], 0, 0, 0);
                acc[m][n] = __builtin_amdgcn_mfma_f32_16x16x32_bf16(ah[m], bl[n], acc[m][n], 0, 0, 0);
                acc[m][n] = __builtin_amdgcn_mfma_f32_16x16x32_bf16(al[m], bh[n], acc[m][n], 0, 0, 0);
            }
        __syncthreads();
    }

    #pragma unroll
    for (int n = 0; n < 4; ++n) {
        int col = bcol + wn*64 + n*16 + l15;
        float bv = bias[col];
        #pragma unroll
        for (int m = 0; m < 4; ++m) {
            int rbs = brow + wm*64 + m*16 + l4*4;
            #pragma unroll
            for (int r = 0; r < 4; ++r)
                C[(size_t)(rbs + r)*N + col] = acc[m][n][r] + bv;
        }
    }
}

// ---------------------------------------------------------------------------
// 3b) Fallback GEMM (in-kernel conversion, fp32 inputs) — Round-4 proven.
// ---------------------------------------------------------------------------
__global__ __launch_bounds__(256) void k_gemm_mfma(const float* __restrict__ A,
                                                   const float* __restrict__ B,
                                                   const float* __restrict__ bias,
                                                   float* __restrict__ C,
                                                   int M, int N, int K)
{
    __shared__ unsigned short As_hi[GBM][40];
    __shared__ unsigned short As_lo[GBM][40];
    __shared__ unsigned int   Bs[GBK][130];

    int tid  = threadIdx.x;
    int brow = blockIdx.y * GBM;
    int bcol = blockIdx.x * GBN;

    int lane = tid & 63;
    int wid  = tid >> 6;
    int wm   = wid >> 1;
    int wn   = wid & 1;
    int l15  = lane & 15;
    int l4   = lane >> 4;

    int a_m = tid >> 3;
    int a_c = tid & 7;
    int b_k = tid >> 5;
    int b_n = tid & 31;

    f32x4 acc[4][4] = {};

    for (int k0 = 0; k0 < K; k0 += GBK) {
        #pragma unroll
        for (int p = 0; p < 4; ++p) {
            int r = a_m + p*32;
            float4 v = *(const float4*)(A + (size_t)(brow + r)*K + k0 + a_c*4);
            unsigned h0 = pack_hi2(v.x, v.y);
            unsigned h1 = pack_hi2(v.z, v.w);
            float lx = v.x - hi_f32(v.x);
            float ly = v.y - hi_f32(v.y);
            float lz = v.z - hi_f32(v.z);
            float lw = v.w - hi_f32(v.w);
            unsigned l0 = pack_hi2(lx, ly);
            unsigned l1 = pack_hi2(lz, lw);
            *(uint2*)&As_hi[r][a_c*4] = make_uint2(h0, h1);
            *(uint2*)&As_lo[r][a_c*4] = make_uint2(l0, l1);
        }
        #pragma unroll
        for (int p = 0; p < 4; ++p) {
            int kk = b_k + p*8;
            float4 v = *(const float4*)(B + (size_t)(k0 + kk)*N + bcol + b_n*4);
            unsigned w0 = pack_pair(v.x);
            unsigned w1 = pack_pair(v.y);
            unsigned w2 = pack_pair(v.z);
            unsigned w3 = pack_pair(v.w);
            *(uint2*)&Bs[kk][b_n*4]     = make_uint2(w0, w1);
            *(uint2*)&Bs[kk][b_n*4 + 2] = make_uint2(w2, w3);
        }
        __syncthreads();

        short8 ah[4], al[4];
        #pragma unroll
        for (int m = 0; m < 4; ++m) {
            int r = wm*64 + m*16 + l15;
            ah[m] = *(const short8*)&As_hi[r][l4*8];
            al[m] = *(const short8*)&As_lo[r][l4*8];
        }

        #pragma unroll
        for (int n = 0; n < 4; ++n) {
            int col = wn*64 + n*16 + l15;
            unsigned w[8];
            #pragma unroll
            for (int j = 0; j < 8; ++j)
                w[j] = Bs[l4*8 + j][col];
            union { short8 v; unsigned d[4]; } bh, bl;
            #pragma unroll
            for (int d = 0; d < 4; ++d) {
                bh.d[d] = (w[2*d] >> 16)      | (w[2*d+1] & 0xFFFF0000u);
                bl.d[d] = (w[2*d] & 0xFFFFu)  | (w[2*d+1] << 16);
            }
            #pragma unroll
            for (int m = 0; m < 4; ++m) {
                acc[m][n] = __builtin_amdgcn_mfma_f32_16x16x32_bf16(ah[m], bh.v, acc[m][n], 0, 0, 0);
                acc[m][n] = __builtin_amdgcn_mfma_f32_16x16x32_bf16(ah[m], bl.v, acc[m][n], 0, 0, 0);
                acc[m][n] = __builtin_amdgcn_mfma_f32_16x16x32_bf16(al[m], bh.v, acc[m][n], 0, 0, 0);
            }
        }
        __syncthreads();
    }

    #pragma unroll
    for (int n = 0; n < 4; ++n) {
        int col = bcol + wn*64 + n*16 + l15;
        float bv = bias[col];
        #pragma unroll
        for (int m = 0; m < 4; ++m) {
            int rb = brow + wm*64 + m*16 + l4*4;
            #pragma unroll
            for (int r = 0; r < 4; ++r)
                C[(size_t)(rb + r)*N + col] = acc[m][n][r] + bv;
        }
    }
}

// ---------------------------------------------------------------------------
// 4) One LSTM timestep — Round-4 version verbatim (proven).
// ---------------------------------------------------------------------------
__global__ __launch_bounds__(256) void k_lstm_step(const float* __restrict__ xg,
                                                   const float* __restrict__ WT,
                                                   float* __restrict__ c_state,
                                                   float* __restrict__ hs,
                                                   int t)
{
    int j    = blockIdx.x;            // hidden col 0..1023
    int gate = threadIdx.x >> 6;      // 0..3 (i,f,g,o)
    int lane = threadIdx.x & 63;
    int col  = gate*HID + j;

    float acc[8] = {};
    if (t > 0) {
        const float4* wv = (const float4*)(WT + (size_t)col*HID);
        #pragma unroll
        for (int c = 0; c < 4; ++c) {
            int k4 = c*64 + lane;
            float4 w4 = wv[k4];
            #pragma unroll
            for (int b = 0; b < 8; ++b) {
                float4 h4 = ((const float4*)(hs + ((size_t)b*SEQ + (t-1))*HID))[k4];
                acc[b] += w4.x*h4.x + w4.y*h4.y + w4.z*h4.z + w4.w*h4.w;
            }
        }
        #pragma unroll
        for (int b = 0; b < 8; ++b) {
            acc[b] += __shfl_xor(acc[b], 32);
            acc[b] += __shfl_xor(acc[b], 16);
            acc[b] += __shfl_xor(acc[b], 8);
            acc[b] += __shfl_xor(acc[b], 4);
            acc[b] += __shfl_xor(acc[b], 2);
            acc[b] += __shfl_xor(acc[b], 1);
        }
    }

    __shared__ float g_sm[4][8];
    if (lane == 0) {
        #pragma unroll
        for (int b = 0; b < 8; ++b)
            g_sm[gate][b] = acc[b];
    }
    __syncthreads();

    if (threadIdx.x < 8) {
        int b = threadIdx.x;
        size_t xbase = ((size_t)b*SEQ + t)*GD + j;
        float iv = g_sm[0][b] + xg[xbase];
        float fv = g_sm[1][b] + xg[xbase + HID];
        float gv = g_sm[2][b] + xg[xbase + 2*HID];
        float ov = g_sm[3][b] + xg[xbase + 3*HID];
        iv = 1.0f / (1.0f + expf(-iv));
        fv = 1.0f / (1.0f + expf(-fv));
        gv = tanhf(gv);
        ov = 1.0f / (1.0f + expf(-ov));
        float c  = (t > 0) ? c_state[(size_t)b*HID + j] : 0.0f;
        float cn = fv*c + iv*gv;
        float hn = ov * tanhf(cn);
        c_state[(size_t)b*HID + j] = cn;
        hs[((size_t)b*SEQ + t)*HID + j] = hn;
    }
}

// ---------------------------------------------------------------------------
// Launch
// ---------------------------------------------------------------------------
extern "C" void kernel_launch(void* const* d_in, const int* in_sizes, int n_in,
                              void* d_out, int out_size, void* d_ws, size_t ws_size,
                              hipStream_t stream)
{
    const int*   ids    = (const int*)  d_in[0];
    const float* w_out  = (const float*)d_in[1];
    const float* b_out  = (const float*)d_in[2];
    const float* W_ih   = (const float*)d_in[3];
    const float* W_hh   = (const float*)d_in[4];
    const float* b_lstm = (const float*)d_in[5];
    float* out = (float*)d_out;

    // d_out scratch (524 MB): every region dead before the final GEMM writes C.
    char* ob = (char*)d_out;
    unsigned short* emb_hi  = (unsigned short*)(ob);               //  8,388,608 B
    unsigned short* emb_lo  = (unsigned short*)(ob + 8388608);     //  8,388,608 B
    float*          WT      = (float*)(ob + 16777216);             // 16,777,216 B
    float*          xg      = (float*)(ob + 33554432);             // 67,108,864 B
    float*          cstate  = (float*)(ob + 100663296);            //     32,768 B
    unsigned short* wih_hiT = (unsigned short*)(ob + 100696064);   //  8,388,608 B
    unsigned short* wih_loT = (unsigned short*)(ob + 109084672);   //  8,388,608 B
    float*          hs_dout = (float*)(ob + 117473280);            // 16,777,216 B

    // d_ws: fast path needs hs_hi/lo + w_out^T hi/lo = 147,849,216 B.
    char* wb = (char*)d_ws;
    const size_t NEED = 147849216ull;
    const bool big_ws = (ws_size >= NEED);
    unsigned short* hs_hi  = (unsigned short*)(wb);                //  8,388,608 B
    unsigned short* hs_lo  = (unsigned short*)(wb + 8388608);      //  8,388,608 B
    unsigned short* wo_hiT = (unsigned short*)(wb + 16777216);     // 65,536,000 B
    unsigned short* wo_loT = (unsigned short*)(wb + 82313216);     // 65,536,000 B
    // hs f32: in d_out on the fast path (dead before final GEMM after split);
    // in d_ws on the fallback path (must stay readable during final GEMM).
    float* hs = big_ws ? hs_dout : (float*)wb;

    // 1) embedding gather (split to hi/lo bf16)
    k_gather_split<<<ROWS, 256, 0, stream>>>(ids, w_out, emb_hi, emb_lo);

    // 2) transpose W_hh (fp32) for the scan
    k_transpose<<<dim3(GD/32, HID/32), dim3(32, 8), 0, stream>>>(W_hh, WT);

    // 2b) W_ih -> transposed hi/lo bf16 [GD][HID]
    k_transsplit<<<dim3(GD/32, HID/32), dim3(32, 8), 0, stream>>>(
        W_ih, wih_hiT, wih_loT, GD);

    // 3) x_gates = emb @ W_ih + b_lstm  (K-major fast MFMA GEMM)
    k_gemm_fast<<<dim3(GD/GBN, ROWS/GBM), 256, 0, stream>>>(
        emb_hi, emb_lo, wih_hiT, wih_loT, b_lstm, xg, ROWS, GD, HID);

    // 4) sequential LSTM scan: 512 launches (launch boundary = HW grid barrier)
    for (int t = 0; t < SEQ; ++t)
        k_lstm_step<<<HID, 256, 0, stream>>>(xg, WT, cstate, hs, t);

    // 5) logits = hs @ w_out + b_out
    if (big_ws) {
        k_transsplit<<<dim3(VOCAB/32, HID/32), dim3(32, 8), 0, stream>>>(
            w_out, wo_hiT, wo_loT, VOCAB);
        k_split_f32<<<1024, 256, 0, stream>>>(hs, hs_hi, hs_lo, (long)ROWS*HID/4);
        k_gemm_fast<<<dim3(VOCAB/GBN, ROWS/GBM), 256, 0, stream>>>(
            hs_hi, hs_lo, wo_hiT, wo_loT, b_out, out, ROWS, VOCAB, HID);
    } else {
        k_gemm_mfma<<<dim3(VOCAB/GBN, ROWS/GBM), 256, 0, stream>>>(
            hs, w_out, b_out, out, ROWS, VOCAB, HID);
    }
}

// Round 9
// 4785.851 us; speedup vs baseline: 3.5585x; 1.0909x over previous
//
#include <hip/hip_runtime.h>
#include <math.h>

#define VOCAB 32000
#define HID   1024
#define BATCH 8
#define SEQ   512
#define GD    (4*HID)       // 4096 gate width
#define ROWS  (BATCH*SEQ)   // 4096

typedef __attribute__((ext_vector_type(8))) short short8;
typedef __attribute__((ext_vector_type(4))) float f32x4;

__device__ __forceinline__ float hi_f32(float x) {
    return __uint_as_float(__float_as_uint(x) & 0xFFFF0000u);
}
// packed word: hi bf16 bits in high half, lo bf16 bits in low half
__device__ __forceinline__ unsigned pack_pair(float x) {
    unsigned hb = __float_as_uint(x) & 0xFFFF0000u;
    float lo = x - __uint_as_float(hb);
    return hb | (__float_as_uint(lo) >> 16);
}
__device__ __forceinline__ unsigned pack_hi2(float x, float y) {
    return (__float_as_uint(x) >> 16) | (__float_as_uint(y) & 0xFFFF0000u);
}

// async 16B/lane global->LDS (dest = wave-uniform base + lane*16)
__device__ __forceinline__ void gload16(const void* g, void* l) {
    __builtin_amdgcn_global_load_lds(
        (__attribute__((address_space(1))) void*)g,
        (__attribute__((address_space(3))) void*)l, 16, 0, 0);
}

// ---------------------------------------------------------------------------
// 1) Embedding gather, split: emb_hi/lo[row][h] = split(w_out[h][ids[row]])
// ---------------------------------------------------------------------------
__global__ __launch_bounds__(256) void k_gather_split(const int* __restrict__ ids,
                                                      const float* __restrict__ w_out,
                                                      unsigned short* __restrict__ emb_hi,
                                                      unsigned short* __restrict__ emb_lo)
{
    int row = blockIdx.x;            // 0..4095
    int id  = ids[row];
    const float* src = w_out + id;   // column id, stride VOCAB
    for (int h = threadIdx.x; h < HID; h += 256) {
        float v  = src[(size_t)h * VOCAB];
        float lo = v - hi_f32(v);
        emb_hi[(size_t)row*HID + h] = (unsigned short)(__float_as_uint(v)  >> 16);
        emb_lo[(size_t)row*HID + h] = (unsigned short)(__float_as_uint(lo) >> 16);
    }
}

// ---------------------------------------------------------------------------
// 2) Transpose W_hh [1024][4096] -> W_hhT [4096][1024] (fp32, for the scan)
// ---------------------------------------------------------------------------
__global__ __launch_bounds__(256) void k_transpose(const float* __restrict__ W,
                                                   float* __restrict__ WT)
{
    __shared__ float tile[32][33];
    int tx = threadIdx.x, ty = threadIdx.y;
    int x = blockIdx.x*32 + tx;
    int y = blockIdx.y*32 + ty;
    #pragma unroll
    for (int i = 0; i < 32; i += 8)
        tile[ty + i][tx] = W[(size_t)(y + i)*GD + x];
    __syncthreads();
    int k   = blockIdx.y*32 + tx;
    int col = blockIdx.x*32 + ty;
    #pragma unroll
    for (int i = 0; i < 32; i += 8)
        WT[(size_t)(col + i)*HID + k] = tile[tx][ty + i];
}

// ---------------------------------------------------------------------------
// 2b) Transpose + split: W[K=1024][N] f32 -> hiT/loT[N][1024] bf16 bits
// ---------------------------------------------------------------------------
__global__ __launch_bounds__(256) void k_transsplit(const float* __restrict__ W,
                                                    unsigned short* __restrict__ hiT,
                                                    unsigned short* __restrict__ loT,
                                                    int N)
{
    __shared__ float tile[32][33];
    int tx = threadIdx.x, ty = threadIdx.y;
    int x = blockIdx.x*32 + tx;      // N
    int y = blockIdx.y*32 + ty;      // K
    #pragma unroll
    for (int i = 0; i < 32; i += 8)
        tile[ty + i][tx] = W[(size_t)(y + i)*N + x];
    __syncthreads();
    int n = blockIdx.x*32 + ty;
    int k = blockIdx.y*32 + tx;
    #pragma unroll
    for (int i = 0; i < 32; i += 8) {
        float v  = tile[tx][ty + i];
        float lo = v - hi_f32(v);
        hiT[(size_t)(n + i)*HID + k] = (unsigned short)(__float_as_uint(v)  >> 16);
        loT[(size_t)(n + i)*HID + k] = (unsigned short)(__float_as_uint(lo) >> 16);
    }
}

// ---------------------------------------------------------------------------
// 2c) Split fp32 -> hi bf16, lo bf16 arrays (grid-stride, float4)
// ---------------------------------------------------------------------------
__global__ __launch_bounds__(256) void k_split_f32(const float* __restrict__ src,
                                                   unsigned short* __restrict__ hi,
                                                   unsigned short* __restrict__ lo,
                                                   long n4)
{
    long i0 = (long)blockIdx.x * 256 + threadIdx.x;
    long stride = (long)gridDim.x * 256;
    for (long i = i0; i < n4; i += stride) {
        float4 v = ((const float4*)src)[i];
        unsigned h0 = __float_as_uint(v.x) >> 16, h1 = __float_as_uint(v.y) >> 16;
        unsigned h2 = __float_as_uint(v.z) >> 16, h3 = __float_as_uint(v.w) >> 16;
        unsigned l0 = __float_as_uint(v.x - hi_f32(v.x)) >> 16;
        unsigned l1 = __float_as_uint(v.y - hi_f32(v.y)) >> 16;
        unsigned l2 = __float_as_uint(v.z - hi_f32(v.z)) >> 16;
        unsigned l3 = __float_as_uint(v.w - hi_f32(v.w)) >> 16;
        ((uint2*)hi)[i] = make_uint2(h0 | (h1 << 16), h2 | (h3 << 16));
        ((uint2*)lo)[i] = make_uint2(l0 | (l1 << 16), l2 | (l3 << 16));
    }
}

// ---------------------------------------------------------------------------
// 3) Fast split-bf16 MFMA GEMM, all operands K-major bf16 bits (R8 proven).
// ---------------------------------------------------------------------------
#define GBM 128
#define GBN 128
#define GBK 32

__global__ __launch_bounds__(256) void k_gemm_fast(
    const unsigned short* __restrict__ Ah,  const unsigned short* __restrict__ Al,
    const unsigned short* __restrict__ BhT, const unsigned short* __restrict__ BlT,
    const float* __restrict__ bias, float* __restrict__ C,
    int M, int N, int K)
{
    __shared__ __align__(16) unsigned short lds[4][4096];  // Ah,Al,Bh,Bl: 8KB each

    const int tid  = threadIdx.x;
    const int lane = tid & 63;
    const int wid  = tid >> 6;
    const int wm = wid >> 1, wn = wid & 1;
    const int l15 = lane & 15, l4 = lane >> 4;
    const int brow = blockIdx.y * GBM;
    const int bcol = blockIdx.x * GBN;

    const int lhi  = lane >> 3;              // 0..7
    const int c8   = (lane & 7) ^ lhi;       // (g&7) == lhi for both chunks
    const int koff = (c8 & 3) * 8;           // element offset in k
    const int r0   = 32*wid + 2*lhi + (c8 >> 2);
    const int r1   = r0 + 16;
    const size_t a0 = (size_t)(brow + r0)*K + koff;
    const size_t a1 = (size_t)(brow + r1)*K + koff;
    const size_t b0 = (size_t)(bcol + r0)*K + koff;
    const size_t b1 = (size_t)(bcol + r1)*K + koff;
    char* lbase = (char*)&lds[0][0];
    const int cb0 = wid*2048, cb1 = wid*2048 + 1024;  // wave-uniform chunk bases

    const int ra = wm*64 + l15;
    const int ga = ra >> 1;
    const int abyte = ga*128 + (((((ra & 1) << 2) | l4) ^ (ga & 7)) << 4);
    const int rb = wn*64 + l15;
    const int gb = rb >> 1;
    const int bbyte = gb*128 + (((((rb & 1) << 2) | l4) ^ (gb & 7)) << 4);

    f32x4 acc[4][4] = {};

    for (int k0 = 0; k0 < K; k0 += GBK) {
        gload16(Ah  + a0 + k0, lbase         + cb0);
        gload16(Ah  + a1 + k0, lbase         + cb1);
        gload16(Al  + a0 + k0, lbase + 8192  + cb0);
        gload16(Al  + a1 + k0, lbase + 8192  + cb1);
        gload16(BhT + b0 + k0, lbase + 16384 + cb0);
        gload16(BhT + b1 + k0, lbase + 16384 + cb1);
        gload16(BlT + b0 + k0, lbase + 24576 + cb0);
        gload16(BlT + b1 + k0, lbase + 24576 + cb1);
        __syncthreads();

        short8 ah[4], al[4], bh[4], bl[4];
        #pragma unroll
        for (int m = 0; m < 4; ++m) {
            ah[m] = *(const short8*)(lbase         + abyte + m*1024);
            al[m] = *(const short8*)(lbase + 8192  + abyte + m*1024);
        }
        #pragma unroll
        for (int n = 0; n < 4; ++n) {
            bh[n] = *(const short8*)(lbase + 16384 + bbyte + n*1024);
            bl[n] = *(const short8*)(lbase + 24576 + bbyte + n*1024);
        }
        #pragma unroll
        for (int n = 0; n < 4; ++n)
            #pragma unroll
            for (int m = 0; m < 4; ++m) {
                acc[m][n] = __builtin_amdgcn_mfma_f32_16x16x32_bf16(ah[m], bh[n], acc[m][n], 0, 0, 0);
                acc[m][n] = __builtin_amdgcn_mfma_f32_16x16x32_bf16(ah[m], bl[n], acc[m][n], 0, 0, 0);
                acc[m][n] = __builtin_amdgcn_mfma_f32_16x16x32_bf16(al[m], bh[n], acc[m][n], 0, 0, 0);
            }
        __syncthreads();
    }

    #pragma unroll
    for (int n = 0; n < 4; ++n) {
        int col = bcol + wn*64 + n*16 + l15;
        float bv = bias[col];
        #pragma unroll
        for (int m = 0; m < 4; ++m) {
            int rbs = brow + wm*64 + m*16 + l4*4;
            #pragma unroll
            for (int r = 0; r < 4; ++r)
                C[(size_t)(rbs + r)*N + col] = acc[m][n][r] + bv;
        }
    }
}

// ---------------------------------------------------------------------------
// 3b) Fallback GEMM (in-kernel conversion, fp32 inputs) — Round-4 proven.
// ---------------------------------------------------------------------------
__global__ __launch_bounds__(256) void k_gemm_mfma(const float* __restrict__ A,
                                                   const float* __restrict__ B,
                                                   const float* __restrict__ bias,
                                                   float* __restrict__ C,
                                                   int M, int N, int K)
{
    __shared__ unsigned short As_hi[GBM][40];
    __shared__ unsigned short As_lo[GBM][40];
    __shared__ unsigned int   Bs[GBK][130];

    int tid  = threadIdx.x;
    int brow = blockIdx.y * GBM;
    int bcol = blockIdx.x * GBN;

    int lane = tid & 63;
    int wid  = tid >> 6;
    int wm   = wid >> 1;
    int wn   = wid & 1;
    int l15  = lane & 15;
    int l4   = lane >> 4;

    int a_m = tid >> 3;
    int a_c = tid & 7;
    int b_k = tid >> 5;
    int b_n = tid & 31;

    f32x4 acc[4][4] = {};

    for (int k0 = 0; k0 < K; k0 += GBK) {
        #pragma unroll
        for (int p = 0; p < 4; ++p) {
            int r = a_m + p*32;
            float4 v = *(const float4*)(A + (size_t)(brow + r)*K + k0 + a_c*4);
            unsigned h0 = pack_hi2(v.x, v.y);
            unsigned h1 = pack_hi2(v.z, v.w);
            float lx = v.x - hi_f32(v.x);
            float ly = v.y - hi_f32(v.y);
            float lz = v.z - hi_f32(v.z);
            float lw = v.w - hi_f32(v.w);
            unsigned l0 = pack_hi2(lx, ly);
            unsigned l1 = pack_hi2(lz, lw);
            *(uint2*)&As_hi[r][a_c*4] = make_uint2(h0, h1);
            *(uint2*)&As_lo[r][a_c*4] = make_uint2(l0, l1);
        }
        #pragma unroll
        for (int p = 0; p < 4; ++p) {
            int kk = b_k + p*8;
            float4 v = *(const float4*)(B + (size_t)(k0 + kk)*N + bcol + b_n*4);
            unsigned w0 = pack_pair(v.x);
            unsigned w1 = pack_pair(v.y);
            unsigned w2 = pack_pair(v.z);
            unsigned w3 = pack_pair(v.w);
            *(uint2*)&Bs[kk][b_n*4]     = make_uint2(w0, w1);
            *(uint2*)&Bs[kk][b_n*4 + 2] = make_uint2(w2, w3);
        }
        __syncthreads();

        short8 ah[4], al[4];
        #pragma unroll
        for (int m = 0; m < 4; ++m) {
            int r = wm*64 + m*16 + l15;
            ah[m] = *(const short8*)&As_hi[r][l4*8];
            al[m] = *(const short8*)&As_lo[r][l4*8];
        }

        #pragma unroll
        for (int n = 0; n < 4; ++n) {
            int col = wn*64 + n*16 + l15;
            unsigned w[8];
            #pragma unroll
            for (int j = 0; j < 8; ++j)
                w[j] = Bs[l4*8 + j][col];
            union { short8 v; unsigned d[4]; } bh, bl;
            #pragma unroll
            for (int d = 0; d < 4; ++d) {
                bh.d[d] = (w[2*d] >> 16)      | (w[2*d+1] & 0xFFFF0000u);
                bl.d[d] = (w[2*d] & 0xFFFFu)  | (w[2*d+1] << 16);
            }
            #pragma unroll
            for (int m = 0; m < 4; ++m) {
                acc[m][n] = __builtin_amdgcn_mfma_f32_16x16x32_bf16(ah[m], bh.v, acc[m][n], 0, 0, 0);
                acc[m][n] = __builtin_amdgcn_mfma_f32_16x16x32_bf16(ah[m], bl.v, acc[m][n], 0, 0, 0);
                acc[m][n] = __builtin_amdgcn_mfma_f32_16x16x32_bf16(al[m], bh.v, acc[m][n], 0, 0, 0);
            }
        }
        __syncthreads();
    }

    #pragma unroll
    for (int n = 0; n < 4; ++n) {
        int col = bcol + wn*64 + n*16 + l15;
        float bv = bias[col];
        #pragma unroll
        for (int m = 0; m < 4; ++m) {
            int rb = brow + wm*64 + m*16 + l4*4;
            #pragma unroll
            for (int r = 0; r < 4; ++r)
                C[(size_t)(rb + r)*N + col] = acc[m][n][r] + bv;
        }
    }
}

// ---------------------------------------------------------------------------
// 4) One LSTM timestep, v3: LDS-staged h + 4 waves/SIMD.
//    Grid: 256 blocks x 1024 thr (16 waves). Block owns 4 hidden cols;
//    wave = (gate, col). h(t-1) staged once per block into LDS (32 KB) ->
//    h-broadcast traffic 32MB -> 8MB/step; W column reads stay coalesced
//    global (L2-hot, read-once). Same per-lane K-partition + butterfly as
//    R4 -> bitwise-identical results. Race-free: reads hs[t-1], writes hs[t].
// ---------------------------------------------------------------------------
__global__ __launch_bounds__(1024) void k_lstm_step(const float* __restrict__ xg,
                                                    const float* __restrict__ WT,
                                                    float* __restrict__ c_state,
                                                    float* __restrict__ hs,
                                                    int t)
{
    __shared__ float h_lds[BATCH*HID];    // 32 KB: h rows [b][k]
    __shared__ float g_sm[4][4][8];       // [gate][col][batch]

    const int tid  = threadIdx.x;
    const int wave = tid >> 6;            // 0..15
    const int lane = tid & 63;
    const int gate = wave >> 2;           // 0..3
    const int jl   = wave & 3;            // 0..3
    const int j0   = blockIdx.x * 4;
    const int j    = j0 + jl;
    const int col  = gate*HID + j;

    float acc[8] = {};
    if (t > 0) {
        // stage h(t-1): 8 rows x 256 float4; thread layout: 128 thr/row, 2 f4 each
        {
            int b   = tid >> 7;           // 0..7
            int off = tid & 127;
            const float4* src = (const float4*)(hs + ((size_t)b*SEQ + (t-1))*HID);
            float4* dst = (float4*)(h_lds + b*HID);
            dst[off]       = src[off];
            dst[off + 128] = src[off + 128];
        }
        __syncthreads();

        const float4* wv = (const float4*)(WT + (size_t)col*HID);
        #pragma unroll
        for (int c = 0; c < 4; ++c) {
            int k4 = c*64 + lane;
            float4 w4 = wv[k4];
            #pragma unroll
            for (int b = 0; b < 8; ++b) {
                float4 h4 = ((const float4*)(h_lds + b*HID))[k4];
                acc[b] += w4.x*h4.x + w4.y*h4.y + w4.z*h4.z + w4.w*h4.w;
            }
        }
        #pragma unroll
        for (int b = 0; b < 8; ++b) {
            acc[b] += __shfl_xor(acc[b], 32);
            acc[b] += __shfl_xor(acc[b], 16);
            acc[b] += __shfl_xor(acc[b], 8);
            acc[b] += __shfl_xor(acc[b], 4);
            acc[b] += __shfl_xor(acc[b], 2);
            acc[b] += __shfl_xor(acc[b], 1);
        }
    }

    if (lane == 0) {
        #pragma unroll
        for (int b = 0; b < 8; ++b)
            g_sm[gate][jl][b] = acc[b];
    }
    __syncthreads();

    if (tid < 32) {
        int b  = tid & 7;
        int jj = tid >> 3;                // 0..3
        int jc = j0 + jj;
        size_t xbase = ((size_t)b*SEQ + t)*GD + jc;
        float iv = g_sm[0][jj][b] + xg[xbase];
        float fv = g_sm[1][jj][b] + xg[xbase + HID];
        float gv = g_sm[2][jj][b] + xg[xbase + 2*HID];
        float ov = g_sm[3][jj][b] + xg[xbase + 3*HID];
        iv = 1.0f / (1.0f + expf(-iv));
        fv = 1.0f / (1.0f + expf(-fv));
        gv = tanhf(gv);
        ov = 1.0f / (1.0f + expf(-ov));
        float c  = (t > 0) ? c_state[(size_t)b*HID + jc] : 0.0f;
        float cn = fv*c + iv*gv;
        float hn = ov * tanhf(cn);
        c_state[(size_t)b*HID + jc] = cn;
        hs[((size_t)b*SEQ + t)*HID + jc] = hn;
    }
}

// ---------------------------------------------------------------------------
// Launch
// ---------------------------------------------------------------------------
extern "C" void kernel_launch(void* const* d_in, const int* in_sizes, int n_in,
                              void* d_out, int out_size, void* d_ws, size_t ws_size,
                              hipStream_t stream)
{
    const int*   ids    = (const int*)  d_in[0];
    const float* w_out  = (const float*)d_in[1];
    const float* b_out  = (const float*)d_in[2];
    const float* W_ih   = (const float*)d_in[3];
    const float* W_hh   = (const float*)d_in[4];
    const float* b_lstm = (const float*)d_in[5];
    float* out = (float*)d_out;

    // d_out scratch (524 MB): every region dead before the final GEMM writes C.
    char* ob = (char*)d_out;
    unsigned short* emb_hi  = (unsigned short*)(ob);               //  8,388,608 B
    unsigned short* emb_lo  = (unsigned short*)(ob + 8388608);     //  8,388,608 B
    float*          WT      = (float*)(ob + 16777216);             // 16,777,216 B
    float*          xg      = (float*)(ob + 33554432);             // 67,108,864 B
    float*          cstate  = (float*)(ob + 100663296);            //     32,768 B
    unsigned short* wih_hiT = (unsigned short*)(ob + 100696064);   //  8,388,608 B
    unsigned short* wih_loT = (unsigned short*)(ob + 109084672);   //  8,388,608 B
    float*          hs_dout = (float*)(ob + 117473280);            // 16,777,216 B

    // d_ws: fast path needs hs_hi/lo + w_out^T hi/lo = 147,849,216 B.
    char* wb = (char*)d_ws;
    const size_t NEED = 147849216ull;
    const bool big_ws = (ws_size >= NEED);
    unsigned short* hs_hi  = (unsigned short*)(wb);                //  8,388,608 B
    unsigned short* hs_lo  = (unsigned short*)(wb + 8388608);      //  8,388,608 B
    unsigned short* wo_hiT = (unsigned short*)(wb + 16777216);     // 65,536,000 B
    unsigned short* wo_loT = (unsigned short*)(wb + 82313216);     // 65,536,000 B
    float* hs = big_ws ? hs_dout : (float*)wb;

    // 1) embedding gather (split to hi/lo bf16)
    k_gather_split<<<ROWS, 256, 0, stream>>>(ids, w_out, emb_hi, emb_lo);

    // 2) transpose W_hh (fp32) for the scan
    k_transpose<<<dim3(GD/32, HID/32), dim3(32, 8), 0, stream>>>(W_hh, WT);

    // 2b) W_ih -> transposed hi/lo bf16 [GD][HID]
    k_transsplit<<<dim3(GD/32, HID/32), dim3(32, 8), 0, stream>>>(
        W_ih, wih_hiT, wih_loT, GD);

    // 3) x_gates = emb @ W_ih + b_lstm  (K-major fast MFMA GEMM)
    k_gemm_fast<<<dim3(GD/GBN, ROWS/GBM), 256, 0, stream>>>(
        emb_hi, emb_lo, wih_hiT, wih_loT, b_lstm, xg, ROWS, GD, HID);

    // 4) sequential LSTM scan: 512 launches (launch boundary = HW grid barrier)
    for (int t = 0; t < SEQ; ++t)
        k_lstm_step<<<HID/4, 1024, 0, stream>>>(xg, WT, cstate, hs, t);

    // 5) logits = hs @ w_out + b_out
    if (big_ws) {
        k_transsplit<<<dim3(VOCAB/32, HID/32), dim3(32, 8), 0, stream>>>(
            w_out, wo_hiT, wo_loT, VOCAB);
        k_split_f32<<<1024, 256, 0, stream>>>(hs, hs_hi, hs_lo, (long)ROWS*HID/4);
        k_gemm_fast<<<dim3(VOCAB/GBN, ROWS/GBM), 256, 0, stream>>>(
            hs_hi, hs_lo, wo_hiT, wo_loT, b_out, out, ROWS, VOCAB, HID);
    } else {
        k_gemm_mfma<<<dim3(VOCAB/GBN, ROWS/GBM), 256, 0, stream>>>(
            hs, w_out, b_out, out, ROWS, VOCAB, HID);
    }
}